// Round 10
// baseline (275.165 us; speedup 1.0000x reference)
//
#include <hip/hip_runtime.h>

#define N_NODES 100000
#define N_EDGES 1000000
#define F_IN 128
#define F_HID 256
#define F_OUT 40
#define GROUP_NODES 12500  // N_NODES / 8 XCD-partition for the CSR fill
#define N_TILES 1563       // ceil(N_NODES / 64)

typedef __attribute__((ext_vector_type(8))) short bf16x8;
typedef __attribute__((ext_vector_type(4))) float f32x4;

__device__ inline unsigned short f2bf(float f) {
    unsigned int u = __float_as_uint(f);
    return (unsigned short)((u + 0x7fffu + ((u >> 16) & 1u)) >> 16);
}
__device__ inline float bflo(unsigned int u) { return __uint_as_float(u << 16); }
__device__ inline float bfhi(unsigned int u) { return __uint_as_float(u & 0xffff0000u); }
__device__ inline unsigned int pack2(float a, float b) {
    return (unsigned int)f2bf(a) | ((unsigned int)f2bf(b) << 16);
}

// ---------------- CSR build (slot-recording count + partitioned fill) ----------------
// rowstart is stored PARTIAL (per-1024-block scan); consumers add boff[i>>10].

__global__ void k_count2(const int* __restrict__ dst, int* __restrict__ cnt,
                         int* __restrict__ slot) {
    int e = blockIdx.x * 256 + threadIdx.x;
    if (e < N_EDGES) slot[e] = atomicAdd(&cnt[dst[e]], 1);
}

__global__ void k_scan_partial(const int* __restrict__ cnt, int* __restrict__ rowstart,
                               float* __restrict__ dinv, int* __restrict__ bsum) {
    __shared__ int wsum[4];
    int tid = threadIdx.x;
    int base = blockIdx.x * 1024 + tid * 4;
    int v[4];
#pragma unroll
    for (int j = 0; j < 4; j++) {
        int i = base + j;
        v[j] = (i < N_NODES) ? cnt[i] : 0;
        if (i < N_NODES) dinv[i] = rsqrtf((float)v[j] + 1.0f);  // +1 self-loop
    }
    int t = v[0] + v[1] + v[2] + v[3];
    int lane = tid & 63, wave = tid >> 6;
    int incl = t;
#pragma unroll
    for (int off = 1; off < 64; off <<= 1) {
        int u = __shfl_up(incl, off);
        if (lane >= off) incl += u;
    }
    if (lane == 63) wsum[wave] = incl;
    __syncthreads();
    int woff = 0;
    for (int w = 0; w < wave; w++) woff += wsum[w];
    int run = woff + incl - t;
#pragma unroll
    for (int j = 0; j < 4; j++) {
        int i = base + j;
        if (i < N_NODES) rowstart[i] = run;
        run += v[j];
    }
    if (tid == 255) bsum[blockIdx.x] = woff + incl;
}

// scan of block sums; last thread also writes rowstart[N_NODES] such that
// rowstart[N_NODES] + boff[N_NODES>>10] == N_EDGES.
__global__ void k_scan_blocks(const int* __restrict__ bsum, int* __restrict__ boff,
                              int* __restrict__ rowstart, int nb) {
    __shared__ int wtot[2];
    int tid = threadIdx.x;
    int v = (tid < nb) ? bsum[tid] : 0;
    int lane = tid & 63, wave = tid >> 6;
    int incl = v;
#pragma unroll
    for (int off = 1; off < 64; off <<= 1) {
        int u = __shfl_up(incl, off);
        if (lane >= off) incl += u;
    }
    if (lane == 63) wtot[wave] = incl;
    __syncthreads();
    int excl = incl - v + (wave ? wtot[0] : 0);
    if (tid < nb) boff[tid] = excl;
    if (tid == nb - 1) rowstart[N_NODES] = N_EDGES - excl;  // N_NODES>>10 == nb-1
}

__global__ void k_fill2(const int* __restrict__ src, const int* __restrict__ dst,
                        const int* __restrict__ slot, const int* __restrict__ rowstart,
                        const int* __restrict__ boff, int* __restrict__ esrc) {
    int g = blockIdx.x & 7;
    int bg = blockIdx.x >> 3;
    int nbg = gridDim.x >> 3;
    int lo = g * GROUP_NODES;
    int hi = lo + GROUP_NODES;
    for (int base = (bg * 256 + threadIdx.x) * 4; base < N_EDGES; base += nbg * 1024) {
        int4 d4 = *(const int4*)(dst + base);
#pragma unroll
        for (int j = 0; j < 4; j++) {
            int d = (&d4.x)[j];
            if (d >= lo && d < hi) {
                int s = src[base + j];
                int sl = slot[base + j];
                esrc[rowstart[d] + boff[d >> 10] + sl] = s;
            }
        }
    }
}

// ---------------- cast (pre-scaled by dinv) + weight prep, one launch ----------------
__global__ void k_cast_prep2(const float* __restrict__ x, const float* __restrict__ dinv,
                             uint2* __restrict__ xb,
                             const float* __restrict__ W1, const float* __restrict__ W2,
                             unsigned short* __restrict__ W1F, unsigned short* __restrict__ W2F) {
    if (blockIdx.x < 12800) {
        int i = blockIdx.x * 256 + threadIdx.x;
        float4 v = ((const float4*)x)[i];
        float d = dinv[i >> 5];
        xb[i] = make_uint2(pack2(d * v.x, d * v.y), pack2(d * v.z, d * v.w));
    } else {
        int i = (blockIdx.x - 12800) * 256 + threadIdx.x;
        if (i < 32768) {
            int j = i & 7, lane = (i >> 3) & 63, mt = (i >> 9) & 7, kc = (i >> 12) & 3, mhalf = i >> 14;
            int l16 = lane & 15, quad = lane >> 4;
            int n = mhalf * 128 + mt * 16 + l16;
            int k = kc * 32 + quad * 8 + j;
            W1F[i] = f2bf(W1[k * F_HID + n]);
        } else {
            int i2 = i - 32768;
            int j = i2 & 7, lane = (i2 >> 3) & 63, mt = (i2 >> 9) & 3, kc = i2 >> 11;
            int l16 = lane & 15, quad = lane >> 4;
            int n = mt * 16 + l16;
            int k = kc * 32 + quad * 8 + j;
            W2F[i2] = (n < F_OUT) ? f2bf(W2[k * F_OUT + n]) : (unsigned short)0;
        }
    }
}

// ---------------- layer 1 aggregation: 16 lanes/node (uint4), 4 nodes/wave ----------------
// 8-edge unroll: ~8 outstanding 16 B gathers per lane.
__global__ void k_agg1(const uint4* __restrict__ xb4, const float* __restrict__ dinv,
                       const int* __restrict__ rowstart, const int* __restrict__ boff,
                       const int* __restrict__ esrc,
                       unsigned short* __restrict__ xaggF) {
    int tile = blockIdx.x;
    int group = threadIdx.x >> 4;  // 16 groups/block
    int l16 = threadIdx.x & 15;
    int kc = l16 >> 2;
    int quad = l16 & 3;
    unsigned short* tbase = xaggF + (size_t)tile * 8192;
    for (int it = 0; it < 4; ++it) {
        int row_local = it * 16 + group;
        int node = tile * 64 + row_local;
        if (node >= N_NODES) break;
        uint4 v = xb4[(size_t)node * 16 + l16];
        float a0 = bflo(v.x), a1 = bfhi(v.x), a2 = bflo(v.y), a3 = bfhi(v.y);
        float a4 = bflo(v.z), a5 = bfhi(v.z), a6 = bflo(v.w), a7 = bfhi(v.w);
        int e0 = rowstart[node] + boff[node >> 10];
        int e1 = rowstart[node + 1] + boff[(node + 1) >> 10];
        int e = e0;
        for (; e + 7 < e1; e += 8) {
            int s0 = esrc[e],     s1 = esrc[e + 1], s2 = esrc[e + 2], s3 = esrc[e + 3];
            int s4 = esrc[e + 4], s5 = esrc[e + 5], s6 = esrc[e + 6], s7 = esrc[e + 7];
            uint4 u0 = xb4[(size_t)s0 * 16 + l16];
            uint4 u1 = xb4[(size_t)s1 * 16 + l16];
            uint4 u2 = xb4[(size_t)s2 * 16 + l16];
            uint4 u3 = xb4[(size_t)s3 * 16 + l16];
            uint4 u4 = xb4[(size_t)s4 * 16 + l16];
            uint4 u5 = xb4[(size_t)s5 * 16 + l16];
            uint4 u6 = xb4[(size_t)s6 * 16 + l16];
            uint4 u7 = xb4[(size_t)s7 * 16 + l16];
            a0 += bflo(u0.x) + bflo(u1.x) + bflo(u2.x) + bflo(u3.x)
                + bflo(u4.x) + bflo(u5.x) + bflo(u6.x) + bflo(u7.x);
            a1 += bfhi(u0.x) + bfhi(u1.x) + bfhi(u2.x) + bfhi(u3.x)
                + bfhi(u4.x) + bfhi(u5.x) + bfhi(u6.x) + bfhi(u7.x);
            a2 += bflo(u0.y) + bflo(u1.y) + bflo(u2.y) + bflo(u3.y)
                + bflo(u4.y) + bflo(u5.y) + bflo(u6.y) + bflo(u7.y);
            a3 += bfhi(u0.y) + bfhi(u1.y) + bfhi(u2.y) + bfhi(u3.y)
                + bfhi(u4.y) + bfhi(u5.y) + bfhi(u6.y) + bfhi(u7.y);
            a4 += bflo(u0.z) + bflo(u1.z) + bflo(u2.z) + bflo(u3.z)
                + bflo(u4.z) + bflo(u5.z) + bflo(u6.z) + bflo(u7.z);
            a5 += bfhi(u0.z) + bfhi(u1.z) + bfhi(u2.z) + bfhi(u3.z)
                + bfhi(u4.z) + bfhi(u5.z) + bfhi(u6.z) + bfhi(u7.z);
            a6 += bflo(u0.w) + bflo(u1.w) + bflo(u2.w) + bflo(u3.w)
                + bflo(u4.w) + bflo(u5.w) + bflo(u6.w) + bflo(u7.w);
            a7 += bfhi(u0.w) + bfhi(u1.w) + bfhi(u2.w) + bfhi(u3.w)
                + bfhi(u4.w) + bfhi(u5.w) + bfhi(u6.w) + bfhi(u7.w);
        }
        for (; e + 3 < e1; e += 4) {
            int s0 = esrc[e], s1 = esrc[e + 1], s2 = esrc[e + 2], s3 = esrc[e + 3];
            uint4 u0 = xb4[(size_t)s0 * 16 + l16];
            uint4 u1 = xb4[(size_t)s1 * 16 + l16];
            uint4 u2 = xb4[(size_t)s2 * 16 + l16];
            uint4 u3 = xb4[(size_t)s3 * 16 + l16];
            a0 += bflo(u0.x) + bflo(u1.x) + bflo(u2.x) + bflo(u3.x);
            a1 += bfhi(u0.x) + bfhi(u1.x) + bfhi(u2.x) + bfhi(u3.x);
            a2 += bflo(u0.y) + bflo(u1.y) + bflo(u2.y) + bflo(u3.y);
            a3 += bfhi(u0.y) + bfhi(u1.y) + bfhi(u2.y) + bfhi(u3.y);
            a4 += bflo(u0.z) + bflo(u1.z) + bflo(u2.z) + bflo(u3.z);
            a5 += bfhi(u0.z) + bfhi(u1.z) + bfhi(u2.z) + bfhi(u3.z);
            a6 += bflo(u0.w) + bflo(u1.w) + bflo(u2.w) + bflo(u3.w);
            a7 += bfhi(u0.w) + bfhi(u1.w) + bfhi(u2.w) + bfhi(u3.w);
        }
        for (; e < e1; ++e) {
            uint4 u = xb4[(size_t)esrc[e] * 16 + l16];
            a0 += bflo(u.x); a1 += bfhi(u.x); a2 += bflo(u.y); a3 += bfhi(u.y);
            a4 += bflo(u.z); a5 += bfhi(u.z); a6 += bflo(u.w); a7 += bfhi(u.w);
        }
        float di = dinv[node];
        a0 *= di; a1 *= di; a2 *= di; a3 *= di;
        a4 *= di; a5 *= di; a6 *= di; a7 *= di;
        int nhalf = row_local >> 5, nt = (row_local >> 4) & 1, l16r = row_local & 15;
        size_t off = (size_t)(kc * 4 + nhalf * 2 + nt) * 512 + (quad * 16 + l16r) * 8;
        *(uint4*)(tbase + off) = make_uint4(pack2(a0, a1), pack2(a2, a3),
                                            pack2(a4, a5), pack2(a6, a7));
    }
}

// ---------------- fused GEMM: h2s = bf16( dinv * (relu(xagg@W1+b1) @ W2) ) ----------------
__launch_bounds__(256)
__global__ void k_fused_gemm(const unsigned short* __restrict__ AF,
                             const unsigned short* __restrict__ W1F,
                             const unsigned short* __restrict__ W2F,
                             const float* __restrict__ b1,
                             const float* __restrict__ dinv,
                             unsigned short* __restrict__ h2b) {
    __shared__ __align__(16) unsigned short Hs[64][264];
    int tid = threadIdx.x;
    int w = tid >> 6, lane = tid & 63;
    int quad = lane >> 4, l16 = lane & 15;
    int row0 = blockIdx.x * 64;
    int mhalf = w >> 1;
    int nhalf = w & 1;
    const unsigned short* AT = AF + (size_t)blockIdx.x * 8192;

    f32x4 acc[2][8];
#pragma unroll
    for (int nt = 0; nt < 2; nt++)
#pragma unroll
        for (int mt = 0; mt < 8; mt++) acc[nt][mt] = (f32x4){0.f, 0.f, 0.f, 0.f};

#pragma unroll
    for (int kc = 0; kc < 4; ++kc) {
        bf16x8 bf[2], af[8];
#pragma unroll
        for (int nt = 0; nt < 2; nt++)
            bf[nt] = *(const bf16x8*)(AT + (size_t)(kc * 4 + nhalf * 2 + nt) * 512 + lane * 8);
#pragma unroll
        for (int mt = 0; mt < 8; mt++)
            af[mt] = *(const bf16x8*)(W1F + (size_t)((mhalf * 4 + kc) * 8 + mt) * 512 + lane * 8);
#pragma unroll
        for (int nt = 0; nt < 2; nt++)
#pragma unroll
            for (int mt = 0; mt < 8; mt++)
                acc[nt][mt] = __builtin_amdgcn_mfma_f32_16x16x32_bf16(af[mt], bf[nt], acc[nt][mt], 0, 0, 0);
    }
#pragma unroll
    for (int mt = 0; mt < 8; mt++) {
        int colbase = mhalf * 128 + mt * 16 + quad * 4;
        float4 bb = *(const float4*)(b1 + colbase);
#pragma unroll
        for (int nt = 0; nt < 2; nt++) {
            int nrow = nhalf * 32 + nt * 16 + l16;
            float v0 = fmaxf(acc[nt][mt][0] + bb.x, 0.f);
            float v1 = fmaxf(acc[nt][mt][1] + bb.y, 0.f);
            float v2 = fmaxf(acc[nt][mt][2] + bb.z, 0.f);
            float v3 = fmaxf(acc[nt][mt][3] + bb.w, 0.f);
            *(uint2*)&Hs[nrow][colbase] = make_uint2(pack2(v0, v1), pack2(v2, v3));
        }
    }
    __syncthreads();

    f32x4 acc2[4];
#pragma unroll
    for (int mt = 0; mt < 4; mt++) acc2[mt] = (f32x4){0.f, 0.f, 0.f, 0.f};
#pragma unroll
    for (int kc = 0; kc < 8; ++kc) {
        int k0 = kc * 32;
        bf16x8 hf = *(const bf16x8*)&Hs[w * 16 + l16][k0 + quad * 8];
        bf16x8 wf[4];
#pragma unroll
        for (int mt = 0; mt < 4; mt++)
            wf[mt] = *(const bf16x8*)(W2F + (size_t)(kc * 4 + mt) * 512 + lane * 8);
#pragma unroll
        for (int mt = 0; mt < 4; mt++)
            acc2[mt] = __builtin_amdgcn_mfma_f32_16x16x32_bf16(wf[mt], hf, acc2[mt], 0, 0, 0);
    }
    int grow = row0 + w * 16 + l16;
    if (grow < N_NODES) {
        float dg = dinv[grow];
#pragma unroll
        for (int mt = 0; mt < 4; mt++) {
            uint2 o = make_uint2(pack2(dg * acc2[mt][0], dg * acc2[mt][1]),
                                 pack2(dg * acc2[mt][2], dg * acc2[mt][3]));
            *(uint2*)(h2b + (size_t)grow * 64 + mt * 16 + quad * 4) = o;
        }
    }
}

// ---------------- layer 2 aggregation + bias + log_softmax: 8 lanes/node ----------------
__global__ void k_agg2(const uint4* __restrict__ h2v4, const float* __restrict__ dinv,
                       const int* __restrict__ rowstart, const int* __restrict__ boff,
                       const int* __restrict__ esrc,
                       const float* __restrict__ b2, float* __restrict__ out) {
    int node = blockIdx.x * 32 + (threadIdx.x >> 3);  // 32 nodes/block (100000 = 3125*32)
    int l8 = threadIdx.x & 7;
    uint4 v = h2v4[(size_t)node * 8 + l8];  // self term (pre-scaled)
    float a0 = bflo(v.x), a1 = bfhi(v.x), a2 = bflo(v.y), a3 = bfhi(v.y);
    float a4 = bflo(v.z), a5 = bfhi(v.z), a6 = bflo(v.w), a7 = bfhi(v.w);
    int e0 = rowstart[node] + boff[node >> 10];
    int e1 = rowstart[node + 1] + boff[(node + 1) >> 10];
    int e = e0;
    for (; e + 7 < e1; e += 8) {
        int s0 = esrc[e],     s1 = esrc[e + 1], s2 = esrc[e + 2], s3 = esrc[e + 3];
        int s4 = esrc[e + 4], s5 = esrc[e + 5], s6 = esrc[e + 6], s7 = esrc[e + 7];
        uint4 u0 = h2v4[(size_t)s0 * 8 + l8];
        uint4 u1 = h2v4[(size_t)s1 * 8 + l8];
        uint4 u2 = h2v4[(size_t)s2 * 8 + l8];
        uint4 u3 = h2v4[(size_t)s3 * 8 + l8];
        uint4 u4 = h2v4[(size_t)s4 * 8 + l8];
        uint4 u5 = h2v4[(size_t)s5 * 8 + l8];
        uint4 u6 = h2v4[(size_t)s6 * 8 + l8];
        uint4 u7 = h2v4[(size_t)s7 * 8 + l8];
        a0 += bflo(u0.x) + bflo(u1.x) + bflo(u2.x) + bflo(u3.x)
            + bflo(u4.x) + bflo(u5.x) + bflo(u6.x) + bflo(u7.x);
        a1 += bfhi(u0.x) + bfhi(u1.x) + bfhi(u2.x) + bfhi(u3.x)
            + bfhi(u4.x) + bfhi(u5.x) + bfhi(u6.x) + bfhi(u7.x);
        a2 += bflo(u0.y) + bflo(u1.y) + bflo(u2.y) + bflo(u3.y)
            + bflo(u4.y) + bflo(u5.y) + bflo(u6.y) + bflo(u7.y);
        a3 += bfhi(u0.y) + bfhi(u1.y) + bfhi(u2.y) + bfhi(u3.y)
            + bfhi(u4.y) + bfhi(u5.y) + bfhi(u6.y) + bfhi(u7.y);
        a4 += bflo(u0.z) + bflo(u1.z) + bflo(u2.z) + bflo(u3.z)
            + bflo(u4.z) + bflo(u5.z) + bflo(u6.z) + bflo(u7.z);
        a5 += bfhi(u0.z) + bfhi(u1.z) + bfhi(u2.z) + bfhi(u3.z)
            + bfhi(u4.z) + bfhi(u5.z) + bfhi(u6.z) + bfhi(u7.z);
        a6 += bflo(u0.w) + bflo(u1.w) + bflo(u2.w) + bflo(u3.w)
            + bflo(u4.w) + bflo(u5.w) + bflo(u6.w) + bflo(u7.w);
        a7 += bfhi(u0.w) + bfhi(u1.w) + bfhi(u2.w) + bfhi(u3.w)
            + bfhi(u4.w) + bfhi(u5.w) + bfhi(u6.w) + bfhi(u7.w);
    }
    for (; e + 3 < e1; e += 4) {
        int s0 = esrc[e], s1 = esrc[e + 1], s2 = esrc[e + 2], s3 = esrc[e + 3];
        uint4 u0 = h2v4[(size_t)s0 * 8 + l8];
        uint4 u1 = h2v4[(size_t)s1 * 8 + l8];
        uint4 u2 = h2v4[(size_t)s2 * 8 + l8];
        uint4 u3 = h2v4[(size_t)s3 * 8 + l8];
        a0 += bflo(u0.x) + bflo(u1.x) + bflo(u2.x) + bflo(u3.x);
        a1 += bfhi(u0.x) + bfhi(u1.x) + bfhi(u2.x) + bfhi(u3.x);
        a2 += bflo(u0.y) + bflo(u1.y) + bflo(u2.y) + bflo(u3.y);
        a3 += bfhi(u0.y) + bfhi(u1.y) + bfhi(u2.y) + bfhi(u3.y);
        a4 += bflo(u0.z) + bflo(u1.z) + bflo(u2.z) + bflo(u3.z);
        a5 += bfhi(u0.z) + bfhi(u1.z) + bfhi(u2.z) + bfhi(u3.z);
        a6 += bflo(u0.w) + bflo(u1.w) + bflo(u2.w) + bflo(u3.w);
        a7 += bfhi(u0.w) + bfhi(u1.w) + bfhi(u2.w) + bfhi(u3.w);
    }
    for (; e < e1; ++e) {
        uint4 u = h2v4[(size_t)esrc[e] * 8 + l8];
        a0 += bflo(u.x); a1 += bfhi(u.x); a2 += bflo(u.y); a3 += bfhi(u.y);
        a4 += bflo(u.z); a5 += bfhi(u.z); a6 += bflo(u.w); a7 += bfhi(u.w);
    }
    float di = dinv[node];
    float vals[8];
    bool act = l8 < 5;  // lanes 0..4 hold the 40 real cols
    if (act) {
        float4 bA = *(const float4*)(b2 + 8 * l8);
        float4 bB = *(const float4*)(b2 + 8 * l8 + 4);
        vals[0] = di * a0 + bA.x; vals[1] = di * a1 + bA.y;
        vals[2] = di * a2 + bA.z; vals[3] = di * a3 + bA.w;
        vals[4] = di * a4 + bB.x; vals[5] = di * a5 + bB.y;
        vals[6] = di * a6 + bB.z; vals[7] = di * a7 + bB.w;
    } else {
#pragma unroll
        for (int j = 0; j < 8; j++) vals[j] = -3.0e38f;
    }
    float m = vals[0];
#pragma unroll
    for (int j = 1; j < 8; j++) m = fmaxf(m, vals[j]);
    m = fmaxf(m, __shfl_xor(m, 1));
    m = fmaxf(m, __shfl_xor(m, 2));
    m = fmaxf(m, __shfl_xor(m, 4));
    float s = 0.0f;
    if (act) {
#pragma unroll
        for (int j = 0; j < 8; j++) s += __expf(vals[j] - m);
    }
    s += __shfl_xor(s, 1);
    s += __shfl_xor(s, 2);
    s += __shfl_xor(s, 4);
    float logs = logf(s);
    if (act) {
        float o0[4] = {vals[0] - m - logs, vals[1] - m - logs, vals[2] - m - logs, vals[3] - m - logs};
        float o1[4] = {vals[4] - m - logs, vals[5] - m - logs, vals[6] - m - logs, vals[7] - m - logs};
        float* ob = out + (size_t)node * F_OUT + 8 * l8;
        *(float4*)ob = *(float4*)o0;
        *(float4*)(ob + 4) = *(float4*)o1;
    }
}

// ---------------- launch ----------------

extern "C" void kernel_launch(void* const* d_in, const int* in_sizes, int n_in,
                              void* d_out, int out_size, void* d_ws, size_t ws_size,
                              hipStream_t stream) {
    const float* x  = (const float*)d_in[0];
    const int* edge = (const int*)d_in[1];
    const float* W1 = (const float*)d_in[2];
    const float* b1 = (const float*)d_in[3];
    const float* W2 = (const float*)d_in[4];
    const float* b2 = (const float*)d_in[5];
    float* out = (float*)d_out;
    const int* src = edge;
    const int* dst = edge + N_EDGES;

    char* ws = (char*)d_ws;
    size_t off = 0;
    auto alloc = [&](size_t bytes) -> void* {
        void* p = ws + off;
        off = (off + bytes + 255) & ~(size_t)255;
        return p;
    };
    float* dinv   = (float*)alloc((size_t)N_NODES * 4);
    int* cnt      = (int*)alloc((size_t)N_NODES * 4);
    int* slot     = (int*)alloc((size_t)N_EDGES * 4);
    int* rowstart = (int*)alloc((size_t)(N_NODES + 1) * 4);
    int* bsum     = (int*)alloc(128 * 4);
    int* boff     = (int*)alloc(128 * 4);
    int* esrc     = (int*)alloc((size_t)N_EDGES * 4);
    unsigned int* xb       = (unsigned int*)alloc((size_t)N_NODES * F_IN * 2);
    unsigned short* xaggF  = (unsigned short*)alloc((size_t)N_TILES * 8192 * 2);
    unsigned short* W1F    = (unsigned short*)alloc((size_t)32768 * 2);
    unsigned short* W2F    = (unsigned short*)alloc((size_t)16384 * 2);
    unsigned short* h2b    = (unsigned short*)alloc((size_t)N_NODES * 64 * 2);
    (void)ws_size; (void)in_sizes; (void)n_in; (void)out_size;

    int nb = (N_NODES + 1023) / 1024;  // 98

    hipMemsetAsync(cnt, 0, (size_t)N_NODES * 4, stream);
    hipLaunchKernelGGL(k_count2, dim3((N_EDGES + 255) / 256), dim3(256), 0, stream, dst, cnt, slot);
    hipLaunchKernelGGL(k_scan_partial, dim3(nb), dim3(256), 0, stream, cnt, rowstart, dinv, bsum);
    hipLaunchKernelGGL(k_scan_blocks, dim3(1), dim3(128), 0, stream, bsum, boff, rowstart, nb);
    hipLaunchKernelGGL(k_fill2, dim3(1024), dim3(256), 0, stream, src, dst, slot, rowstart, boff, esrc);
    hipLaunchKernelGGL(k_cast_prep2, dim3(12992), dim3(256), 0, stream,
                       x, dinv, (uint2*)xb, W1, W2, W1F, W2F);
    hipLaunchKernelGGL(k_agg1, dim3(N_TILES), dim3(256), 0, stream,
                       (const uint4*)xb, dinv, rowstart, boff, esrc, xaggF);
    hipLaunchKernelGGL(k_fused_gemm, dim3(N_TILES), dim3(256), 0, stream,
                       xaggF, W1F, W2F, b1, dinv, h2b);
    hipLaunchKernelGGL(k_agg2, dim3(N_NODES / 32), dim3(256), 0, stream,
                       (const uint4*)h2b, dinv, rowstart, boff, esrc, b2, out);
}

// Round 11
// 260.589 us; speedup vs baseline: 1.0559x; 1.0559x over previous
//
#include <hip/hip_runtime.h>

#define N_NODES 100000
#define N_EDGES 1000000
#define F_IN 128
#define F_HID 256
#define F_OUT 40
#define GROUP_NODES 12500  // N_NODES / 8 XCD-partition for the CSR fill
#define N_TILES 1563       // ceil(N_NODES / 64)

typedef __attribute__((ext_vector_type(8))) short bf16x8;
typedef __attribute__((ext_vector_type(4))) float f32x4;

__device__ inline unsigned short f2bf(float f) {
    unsigned int u = __float_as_uint(f);
    return (unsigned short)((u + 0x7fffu + ((u >> 16) & 1u)) >> 16);
}
__device__ inline float bflo(unsigned int u) { return __uint_as_float(u << 16); }
__device__ inline float bfhi(unsigned int u) { return __uint_as_float(u & 0xffff0000u); }
__device__ inline unsigned int pack2(float a, float b) {
    return (unsigned int)f2bf(a) | ((unsigned int)f2bf(b) << 16);
}

// ---------------- CSR build ----------------
// rowstart is PARTIAL (per-1024-node block scan); consumers add boff[i>>10].
// count2 records rec[e] = (slot<<17) | src  (src < 2^17, slot < 2^15 guaranteed).

__global__ void k_count2(const int* __restrict__ src, const int* __restrict__ dst,
                         int* __restrict__ cnt, unsigned int* __restrict__ rec) {
    int e = blockIdx.x * 256 + threadIdx.x;
    if (e < N_EDGES) {
        int sl = atomicAdd(&cnt[dst[e]], 1);
        rec[e] = ((unsigned int)sl << 17) | (unsigned int)src[e];
    }
}

__global__ void k_scan_partial(const int* __restrict__ cnt, int* __restrict__ rowstart,
                               float* __restrict__ dinv, int* __restrict__ bsum) {
    __shared__ int wsum[4];
    int tid = threadIdx.x;
    int base = blockIdx.x * 1024 + tid * 4;
    int v[4];
#pragma unroll
    for (int j = 0; j < 4; j++) {
        int i = base + j;
        v[j] = (i < N_NODES) ? cnt[i] : 0;
        if (i < N_NODES) dinv[i] = rsqrtf((float)v[j] + 1.0f);  // +1 self-loop
    }
    int t = v[0] + v[1] + v[2] + v[3];
    int lane = tid & 63, wave = tid >> 6;
    int incl = t;
#pragma unroll
    for (int off = 1; off < 64; off <<= 1) {
        int u = __shfl_up(incl, off);
        if (lane >= off) incl += u;
    }
    if (lane == 63) wsum[wave] = incl;
    __syncthreads();
    int woff = 0;
    for (int w = 0; w < wave; w++) woff += wsum[w];
    int run = woff + incl - t;
#pragma unroll
    for (int j = 0; j < 4; j++) {
        int i = base + j;
        if (i < N_NODES) rowstart[i] = run;
        run += v[j];
    }
    if (tid == 255) bsum[blockIdx.x] = woff + incl;
}

// scan of block sums; also writes rowstart[N_NODES] so that
// rowstart[N_NODES] + boff[N_NODES>>10] == N_EDGES.
__global__ void k_scan_blocks(const int* __restrict__ bsum, int* __restrict__ boff,
                              int* __restrict__ rowstart, int nb) {
    __shared__ int wtot[2];
    int tid = threadIdx.x;
    int v = (tid < nb) ? bsum[tid] : 0;
    int lane = tid & 63, wave = tid >> 6;
    int incl = v;
#pragma unroll
    for (int off = 1; off < 64; off <<= 1) {
        int u = __shfl_up(incl, off);
        if (lane >= off) incl += u;
    }
    if (lane == 63) wtot[wave] = incl;
    __syncthreads();
    int excl = incl - v + (wave ? wtot[0] : 0);
    if (tid < nb) boff[tid] = excl;
    if (tid == nb - 1) rowstart[N_NODES] = N_EDGES - excl;  // N_NODES>>10 == nb-1
}

// ---------------- fused: XCD-partitioned fill + x cast + W prep (one dispatch) ----------------
// blocks [0,1024): fill  — group g=blockIdx&7 owns dst range, atomic-free scatter
// blocks [1024,13524): cast xs = bf16(dinv*x), one float4/thread (exact, 12500 blocks)
// blocks [13524,13716): W1F/W2F MFMA-fragment-order transform
__global__ void k_fill_cast(const int* __restrict__ dst, const unsigned int* __restrict__ rec,
                            const int* __restrict__ rowstart, const int* __restrict__ boff,
                            int* __restrict__ esrc,
                            const float* __restrict__ x, const float* __restrict__ dinv,
                            uint2* __restrict__ xb,
                            const float* __restrict__ W1, const float* __restrict__ W2,
                            unsigned short* __restrict__ W1F, unsigned short* __restrict__ W2F) {
    int b = blockIdx.x;
    if (b < 1024) {
        int g = b & 7;
        int bg = b >> 3;
        int lo = g * GROUP_NODES;
        int hi = lo + GROUP_NODES;
        for (int base = (bg * 256 + threadIdx.x) * 4; base < N_EDGES; base += 128 * 1024) {
            int4 d4 = *(const int4*)(dst + base);
#pragma unroll
            for (int j = 0; j < 4; j++) {
                int d = (&d4.x)[j];
                if (d >= lo && d < hi) {
                    unsigned int r = rec[base + j];
                    esrc[rowstart[d] + boff[d >> 10] + (int)(r >> 17)] = (int)(r & 0x1FFFFu);
                }
            }
        }
    } else if (b < 13524) {
        int i = (b - 1024) * 256 + threadIdx.x;  // [0, 3.2M) exact
        float4 v = ((const float4*)x)[i];
        float d = dinv[i >> 5];  // node = i*4/128
        xb[i] = make_uint2(pack2(d * v.x, d * v.y), pack2(d * v.z, d * v.w));
    } else {
        int i = (b - 13524) * 256 + threadIdx.x;  // [0, 49152)
        if (i < 32768) {
            int j = i & 7, lane = (i >> 3) & 63, mt = (i >> 9) & 7, kc = (i >> 12) & 3, mhalf = i >> 14;
            int l16 = lane & 15, quad = lane >> 4;
            int n = mhalf * 128 + mt * 16 + l16;
            int k = kc * 32 + quad * 8 + j;
            W1F[i] = f2bf(W1[k * F_HID + n]);
        } else {
            int i2 = i - 32768;
            int j = i2 & 7, lane = (i2 >> 3) & 63, mt = (i2 >> 9) & 3, kc = i2 >> 11;
            int l16 = lane & 15, quad = lane >> 4;
            int n = mt * 16 + l16;
            int k = kc * 32 + quad * 8 + j;
            W2F[i2] = (n < F_OUT) ? f2bf(W2[k * F_OUT + n]) : (unsigned short)0;
        }
    }
}

// ---------------- layer 1 aggregation: 16 lanes/node (uint4), 4 nodes/wave, 4-edge unroll ----------------
__global__ void k_agg1(const uint4* __restrict__ xb4, const float* __restrict__ dinv,
                       const int* __restrict__ rowstart, const int* __restrict__ boff,
                       const int* __restrict__ esrc,
                       unsigned short* __restrict__ xaggF) {
    int tile = blockIdx.x;
    int group = threadIdx.x >> 4;  // 16 groups/block
    int l16 = threadIdx.x & 15;
    int kc = l16 >> 2;
    int quad = l16 & 3;
    unsigned short* tbase = xaggF + (size_t)tile * 8192;
    for (int it = 0; it < 4; ++it) {
        int row_local = it * 16 + group;
        int node = tile * 64 + row_local;
        if (node >= N_NODES) break;
        uint4 v = xb4[(size_t)node * 16 + l16];
        float a0 = bflo(v.x), a1 = bfhi(v.x), a2 = bflo(v.y), a3 = bfhi(v.y);
        float a4 = bflo(v.z), a5 = bfhi(v.z), a6 = bflo(v.w), a7 = bfhi(v.w);
        int e0 = rowstart[node] + boff[node >> 10];
        int e1 = rowstart[node + 1] + boff[(node + 1) >> 10];
        int e = e0;
        for (; e + 3 < e1; e += 4) {
            int s0 = esrc[e], s1 = esrc[e + 1], s2 = esrc[e + 2], s3 = esrc[e + 3];
            uint4 u0 = xb4[(size_t)s0 * 16 + l16];
            uint4 u1 = xb4[(size_t)s1 * 16 + l16];
            uint4 u2 = xb4[(size_t)s2 * 16 + l16];
            uint4 u3 = xb4[(size_t)s3 * 16 + l16];
            a0 += bflo(u0.x) + bflo(u1.x) + bflo(u2.x) + bflo(u3.x);
            a1 += bfhi(u0.x) + bfhi(u1.x) + bfhi(u2.x) + bfhi(u3.x);
            a2 += bflo(u0.y) + bflo(u1.y) + bflo(u2.y) + bflo(u3.y);
            a3 += bfhi(u0.y) + bfhi(u1.y) + bfhi(u2.y) + bfhi(u3.y);
            a4 += bflo(u0.z) + bflo(u1.z) + bflo(u2.z) + bflo(u3.z);
            a5 += bfhi(u0.z) + bfhi(u1.z) + bfhi(u2.z) + bfhi(u3.z);
            a6 += bflo(u0.w) + bflo(u1.w) + bflo(u2.w) + bflo(u3.w);
            a7 += bfhi(u0.w) + bfhi(u1.w) + bfhi(u2.w) + bfhi(u3.w);
        }
        for (; e < e1; ++e) {
            uint4 u = xb4[(size_t)esrc[e] * 16 + l16];
            a0 += bflo(u.x); a1 += bfhi(u.x); a2 += bflo(u.y); a3 += bfhi(u.y);
            a4 += bflo(u.z); a5 += bfhi(u.z); a6 += bflo(u.w); a7 += bfhi(u.w);
        }
        float di = dinv[node];
        a0 *= di; a1 *= di; a2 *= di; a3 *= di;
        a4 *= di; a5 *= di; a6 *= di; a7 *= di;
        int nhalf = row_local >> 5, nt = (row_local >> 4) & 1, l16r = row_local & 15;
        size_t off = (size_t)(kc * 4 + nhalf * 2 + nt) * 512 + (quad * 16 + l16r) * 8;
        *(uint4*)(tbase + off) = make_uint4(pack2(a0, a1), pack2(a2, a3),
                                            pack2(a4, a5), pack2(a6, a7));
    }
}

// ---------------- fused GEMM: h2s = bf16( dinv * (relu(xagg@W1+b1) @ W2) ) ----------------
__launch_bounds__(256)
__global__ void k_fused_gemm(const unsigned short* __restrict__ AF,
                             const unsigned short* __restrict__ W1F,
                             const unsigned short* __restrict__ W2F,
                             const float* __restrict__ b1,
                             const float* __restrict__ dinv,
                             unsigned short* __restrict__ h2b) {
    __shared__ __align__(16) unsigned short Hs[64][264];
    int tid = threadIdx.x;
    int w = tid >> 6, lane = tid & 63;
    int quad = lane >> 4, l16 = lane & 15;
    int row0 = blockIdx.x * 64;
    int mhalf = w >> 1;
    int nhalf = w & 1;
    const unsigned short* AT = AF + (size_t)blockIdx.x * 8192;

    f32x4 acc[2][8];
#pragma unroll
    for (int nt = 0; nt < 2; nt++)
#pragma unroll
        for (int mt = 0; mt < 8; mt++) acc[nt][mt] = (f32x4){0.f, 0.f, 0.f, 0.f};

#pragma unroll
    for (int kc = 0; kc < 4; ++kc) {
        bf16x8 bf[2], af[8];
#pragma unroll
        for (int nt = 0; nt < 2; nt++)
            bf[nt] = *(const bf16x8*)(AT + (size_t)(kc * 4 + nhalf * 2 + nt) * 512 + lane * 8);
#pragma unroll
        for (int mt = 0; mt < 8; mt++)
            af[mt] = *(const bf16x8*)(W1F + (size_t)((mhalf * 4 + kc) * 8 + mt) * 512 + lane * 8);
#pragma unroll
        for (int nt = 0; nt < 2; nt++)
#pragma unroll
            for (int mt = 0; mt < 8; mt++)
                acc[nt][mt] = __builtin_amdgcn_mfma_f32_16x16x32_bf16(af[mt], bf[nt], acc[nt][mt], 0, 0, 0);
    }
#pragma unroll
    for (int mt = 0; mt < 8; mt++) {
        int colbase = mhalf * 128 + mt * 16 + quad * 4;
        float4 bb = *(const float4*)(b1 + colbase);
#pragma unroll
        for (int nt = 0; nt < 2; nt++) {
            int nrow = nhalf * 32 + nt * 16 + l16;
            float v0 = fmaxf(acc[nt][mt][0] + bb.x, 0.f);
            float v1 = fmaxf(acc[nt][mt][1] + bb.y, 0.f);
            float v2 = fmaxf(acc[nt][mt][2] + bb.z, 0.f);
            float v3 = fmaxf(acc[nt][mt][3] + bb.w, 0.f);
            *(uint2*)&Hs[nrow][colbase] = make_uint2(pack2(v0, v1), pack2(v2, v3));
        }
    }
    __syncthreads();

    f32x4 acc2[4];
#pragma unroll
    for (int mt = 0; mt < 4; mt++) acc2[mt] = (f32x4){0.f, 0.f, 0.f, 0.f};
#pragma unroll
    for (int kc = 0; kc < 8; ++kc) {
        int k0 = kc * 32;
        bf16x8 hf = *(const bf16x8*)&Hs[w * 16 + l16][k0 + quad * 8];
        bf16x8 wf[4];
#pragma unroll
        for (int mt = 0; mt < 4; mt++)
            wf[mt] = *(const bf16x8*)(W2F + (size_t)(kc * 4 + mt) * 512 + lane * 8);
#pragma unroll
        for (int mt = 0; mt < 4; mt++)
            acc2[mt] = __builtin_amdgcn_mfma_f32_16x16x32_bf16(wf[mt], hf, acc2[mt], 0, 0, 0);
    }
    int grow = row0 + w * 16 + l16;
    if (grow < N_NODES) {
        float dg = dinv[grow];
#pragma unroll
        for (int mt = 0; mt < 4; mt++) {
            uint2 o = make_uint2(pack2(dg * acc2[mt][0], dg * acc2[mt][1]),
                                 pack2(dg * acc2[mt][2], dg * acc2[mt][3]));
            *(uint2*)(h2b + (size_t)grow * 64 + mt * 16 + quad * 4) = o;
        }
    }
}

// ---------------- layer 2 aggregation + bias + log_softmax: 8 lanes/node, 4-edge unroll ----------------
__global__ void k_agg2(const uint4* __restrict__ h2v4, const float* __restrict__ dinv,
                       const int* __restrict__ rowstart, const int* __restrict__ boff,
                       const int* __restrict__ esrc,
                       const float* __restrict__ b2, float* __restrict__ out) {
    int node = blockIdx.x * 32 + (threadIdx.x >> 3);  // 32 nodes/block (100000 = 3125*32)
    int l8 = threadIdx.x & 7;
    uint4 v = h2v4[(size_t)node * 8 + l8];  // self term (pre-scaled)
    float a0 = bflo(v.x), a1 = bfhi(v.x), a2 = bflo(v.y), a3 = bfhi(v.y);
    float a4 = bflo(v.z), a5 = bfhi(v.z), a6 = bflo(v.w), a7 = bfhi(v.w);
    int e0 = rowstart[node] + boff[node >> 10];
    int e1 = rowstart[node + 1] + boff[(node + 1) >> 10];
    int e = e0;
    for (; e + 3 < e1; e += 4) {
        int s0 = esrc[e], s1 = esrc[e + 1], s2 = esrc[e + 2], s3 = esrc[e + 3];
        uint4 u0 = h2v4[(size_t)s0 * 8 + l8];
        uint4 u1 = h2v4[(size_t)s1 * 8 + l8];
        uint4 u2 = h2v4[(size_t)s2 * 8 + l8];
        uint4 u3 = h2v4[(size_t)s3 * 8 + l8];
        a0 += bflo(u0.x) + bflo(u1.x) + bflo(u2.x) + bflo(u3.x);
        a1 += bfhi(u0.x) + bfhi(u1.x) + bfhi(u2.x) + bfhi(u3.x);
        a2 += bflo(u0.y) + bflo(u1.y) + bflo(u2.y) + bflo(u3.y);
        a3 += bfhi(u0.y) + bfhi(u1.y) + bfhi(u2.y) + bfhi(u3.y);
        a4 += bflo(u0.z) + bflo(u1.z) + bflo(u2.z) + bflo(u3.z);
        a5 += bfhi(u0.z) + bfhi(u1.z) + bfhi(u2.z) + bfhi(u3.z);
        a6 += bflo(u0.w) + bflo(u1.w) + bflo(u2.w) + bflo(u3.w);
        a7 += bfhi(u0.w) + bfhi(u1.w) + bfhi(u2.w) + bfhi(u3.w);
    }
    for (; e < e1; ++e) {
        uint4 u = h2v4[(size_t)esrc[e] * 8 + l8];
        a0 += bflo(u.x); a1 += bfhi(u.x); a2 += bflo(u.y); a3 += bfhi(u.y);
        a4 += bflo(u.z); a5 += bfhi(u.z); a6 += bflo(u.w); a7 += bfhi(u.w);
    }
    float di = dinv[node];
    float vals[8];
    bool act = l8 < 5;  // lanes 0..4 hold the 40 real cols
    if (act) {
        float4 bA = *(const float4*)(b2 + 8 * l8);
        float4 bB = *(const float4*)(b2 + 8 * l8 + 4);
        vals[0] = di * a0 + bA.x; vals[1] = di * a1 + bA.y;
        vals[2] = di * a2 + bA.z; vals[3] = di * a3 + bA.w;
        vals[4] = di * a4 + bB.x; vals[5] = di * a5 + bB.y;
        vals[6] = di * a6 + bB.z; vals[7] = di * a7 + bB.w;
    } else {
#pragma unroll
        for (int j = 0; j < 8; j++) vals[j] = -3.0e38f;
    }
    float m = vals[0];
#pragma unroll
    for (int j = 1; j < 8; j++) m = fmaxf(m, vals[j]);
    m = fmaxf(m, __shfl_xor(m, 1));
    m = fmaxf(m, __shfl_xor(m, 2));
    m = fmaxf(m, __shfl_xor(m, 4));
    float s = 0.0f;
    if (act) {
#pragma unroll
        for (int j = 0; j < 8; j++) s += __expf(vals[j] - m);
    }
    s += __shfl_xor(s, 1);
    s += __shfl_xor(s, 2);
    s += __shfl_xor(s, 4);
    float logs = logf(s);
    if (act) {
        float o0[4] = {vals[0] - m - logs, vals[1] - m - logs, vals[2] - m - logs, vals[3] - m - logs};
        float o1[4] = {vals[4] - m - logs, vals[5] - m - logs, vals[6] - m - logs, vals[7] - m - logs};
        float* ob = out + (size_t)node * F_OUT + 8 * l8;
        *(float4*)ob = *(float4*)o0;
        *(float4*)(ob + 4) = *(float4*)o1;
    }
}

// ---------------- launch ----------------

extern "C" void kernel_launch(void* const* d_in, const int* in_sizes, int n_in,
                              void* d_out, int out_size, void* d_ws, size_t ws_size,
                              hipStream_t stream) {
    const float* x  = (const float*)d_in[0];
    const int* edge = (const int*)d_in[1];
    const float* W1 = (const float*)d_in[2];
    const float* b1 = (const float*)d_in[3];
    const float* W2 = (const float*)d_in[4];
    const float* b2 = (const float*)d_in[5];
    float* out = (float*)d_out;
    const int* src = edge;
    const int* dst = edge + N_EDGES;

    char* ws = (char*)d_ws;
    size_t off = 0;
    auto alloc = [&](size_t bytes) -> void* {
        void* p = ws + off;
        off = (off + bytes + 255) & ~(size_t)255;
        return p;
    };
    float* dinv   = (float*)alloc((size_t)N_NODES * 4);
    int* cnt      = (int*)alloc((size_t)N_NODES * 4);
    unsigned int* rec = (unsigned int*)alloc((size_t)N_EDGES * 4);  // (slot<<17)|src
    int* rowstart = (int*)alloc((size_t)(N_NODES + 1) * 4);
    int* bsum     = (int*)alloc(128 * 4);
    int* boff     = (int*)alloc(128 * 4);
    int* esrc     = (int*)alloc((size_t)N_EDGES * 4);
    unsigned int* xb       = (unsigned int*)alloc((size_t)N_NODES * F_IN * 2);
    unsigned short* xaggF  = (unsigned short*)alloc((size_t)N_TILES * 8192 * 2);
    unsigned short* W1F    = (unsigned short*)alloc((size_t)32768 * 2);
    unsigned short* W2F    = (unsigned short*)alloc((size_t)16384 * 2);
    unsigned short* h2b    = (unsigned short*)alloc((size_t)N_NODES * 64 * 2);
    (void)ws_size; (void)in_sizes; (void)n_in; (void)out_size;

    int nb = (N_NODES + 1023) / 1024;  // 98

    hipMemsetAsync(cnt, 0, (size_t)N_NODES * 4, stream);
    hipLaunchKernelGGL(k_count2, dim3((N_EDGES + 255) / 256), dim3(256), 0, stream, src, dst, cnt, rec);
    hipLaunchKernelGGL(k_scan_partial, dim3(nb), dim3(256), 0, stream, cnt, rowstart, dinv, bsum);
    hipLaunchKernelGGL(k_scan_blocks, dim3(1), dim3(128), 0, stream, bsum, boff, rowstart, nb);
    hipLaunchKernelGGL(k_fill_cast, dim3(13716), dim3(256), 0, stream,
                       dst, rec, rowstart, boff, esrc, x, dinv, (uint2*)xb, W1, W2, W1F, W2F);
    hipLaunchKernelGGL(k_agg1, dim3(N_TILES), dim3(256), 0, stream,
                       (const uint4*)xb, dinv, rowstart, boff, esrc, xaggF);
    hipLaunchKernelGGL(k_fused_gemm, dim3(N_TILES), dim3(256), 0, stream,
                       xaggF, W1F, W2F, b1, dinv, h2b);
    hipLaunchKernelGGL(k_agg2, dim3(N_NODES / 32), dim3(256), 0, stream,
                       (const uint4*)h2b, dinv, rowstart, boff, esrc, b2, out);
}